// Round 5
// baseline (506.592 us; speedup 1.0000x reference)
//
#include <hip/hip_runtime.h>
#include <math.h>

static constexpr int N_NODES = 100000;
static constexpr int D = 64;
static constexpr int NB_SETUP = 512;                                  // co-resident blocks
static constexpr int NPB = (N_NODES + NB_SETUP - 1) / NB_SETUP;       // 196 nodes/block

typedef float  f32x4 __attribute__((ext_vector_type(4)));
typedef short  s16x8 __attribute__((ext_vector_type(8)));

__device__ __forceinline__ unsigned short f2bf(float f) {
    unsigned u = __float_as_uint(f);
    return (unsigned short)((u + 0x7FFFu + ((u >> 16) & 1u)) >> 16);
}
__device__ __forceinline__ float bf2f(unsigned short s) {
    return __uint_as_float(((unsigned)s) << 16);
}

// Device-scope grid barrier: monotonic counter, no reset (no ABA).
// Co-residency guaranteed: 512 blocks, __launch_bounds__(256,2) => >=2 blocks/CU capacity.
__device__ __forceinline__ void gbar(unsigned* cnt, unsigned target) {
    __syncthreads();
    __threadfence();                     // release my block's writes to device scope
    if (threadIdx.x == 0) {
        atomicAdd(cnt, 1u);
        while (__hip_atomic_load(cnt, __ATOMIC_RELAXED, __HIP_MEMORY_SCOPE_AGENT) < target)
            __builtin_amdgcn_s_sleep(8);
    }
    __syncthreads();
    __threadfence();                     // acquire: invalidate caches, see others' writes
}

// ONE kernel: zero -> mark -> degcount -> scan/CSR -> scatter (5 grid barriers).
__global__ __launch_bounds__(256, 2) void setup_kernel(
    const int* __restrict__ nodes, const int* __restrict__ dst,
    unsigned* __restrict__ slot,      // [N] followed contiguously by deg [N]
    unsigned* __restrict__ deg,
    unsigned* __restrict__ csr_off, unsigned* __restrict__ cursor,
    unsigned* __restrict__ nrank, int* __restrict__ nlist,
    unsigned* __restrict__ bsum, unsigned* __restrict__ bnz,
    unsigned* __restrict__ nflag, int* __restrict__ cedge,
    unsigned* __restrict__ barcnt, int E, int B)
{
    const int tid = threadIdx.x;
    const int gtid = blockIdx.x * 256 + tid;
    const int NT = NB_SETUP * 256;

    // P0: zero slot+deg (contiguous 2N words starting at slot)
    for (int i = gtid; i < 2 * N_NODES; i += NT) slot[i] = 0u;
    gbar(barcnt, NB_SETUP * 1);

    // P1: mark requested nodes (plain store, idempotent)
    for (int b = gtid; b < B; b += NT) slot[nodes[b]] = 1u;
    gbar(barcnt, NB_SETUP * 2);

    // P2: per-dst degree of flagged edges
    for (int e = gtid; e < E; e += NT) {
        int d = dst[e];
        if (slot[d] != 0u) atomicAdd(&deg[d], 1u);
    }
    gbar(barcnt, NB_SETUP * 3);

    // P3a: block-local exclusive scan over this block's NPB nodes (one round, NPB<=256)
    const int lane = tid & 63, w = tid >> 6;
    const int i = blockIdx.x * NPB + tid;
    unsigned v = (tid < NPB && i < N_NODES) ? deg[i] : 0u;
    unsigned p = v;
    #pragma unroll
    for (int off = 1; off < 64; off <<= 1) {
        unsigned t = __shfl_up(p, off);
        if (lane >= off) p += t;
    }
    bool nz = v > 0u;
    unsigned long long mb = __ballot(nz);
    unsigned lower = __popcll(mb & ((1ull << lane) - 1ull));
    __shared__ unsigned wsE[4], wsZ[4];
    if (lane == 63) { wsE[w] = p; wsZ[w] = (unsigned)__popcll(mb); }
    __syncthreads();
    unsigned woffE = 0, woffZ = 0;
    for (int ww = 0; ww < w; ++ww) { woffE += wsE[ww]; woffZ += wsZ[ww]; }
    const unsigned excl = woffE + p - v;
    const unsigned nzr  = woffZ + lower;
    if (tid == 0) {
        bsum[blockIdx.x] = wsE[0] + wsE[1] + wsE[2] + wsE[3];
        bnz[blockIdx.x]  = wsZ[0] + wsZ[1] + wsZ[2] + wsZ[3];
    }
    gbar(barcnt, NB_SETUP * 4);

    // P3b: global offsets via masked reduction over 512 block sums
    unsigned se = 0, szv = 0, tz = 0;
    for (int k = tid; k < NB_SETUP; k += 256) {
        unsigned be = bsum[k], bz = bnz[k];
        tz += bz;
        if (k < (int)blockIdx.x) { se += be; szv += bz; }
    }
    #pragma unroll
    for (int off = 32; off; off >>= 1) {
        se  += __shfl_down(se, off);
        szv += __shfl_down(szv, off);
        tz  += __shfl_down(tz, off);
    }
    __shared__ unsigned rA[4], rB[4], rC[4];
    if (lane == 0) { rA[w] = se; rB[w] = szv; rC[w] = tz; }
    __syncthreads();
    const unsigned off_e = rA[0] + rA[1] + rA[2] + rA[3];
    const unsigned off_z = rB[0] + rB[1] + rB[2] + rB[3];
    if (blockIdx.x == 0 && tid == 0) *nflag = rC[0] + rC[1] + rC[2] + rC[3];

    // P3c: write CSR arrays + flagged-node list + node->rank map
    if (tid < NPB && i < N_NODES) {
        unsigned o = off_e + excl;
        csr_off[i] = o;
        cursor[i] = o;
        if (nz) { unsigned r = off_z + nzr; nlist[r] = i; nrank[i] = r; }
        else nrank[i] = 0xFFFFFFFFu;
    }
    gbar(barcnt, NB_SETUP * 5);

    // P4: scatter flagged edges into per-dst CSR lists
    for (int e = gtid; e < E; e += NT) {
        int d = dst[e];
        if (slot[d] != 0u) {
            unsigned pos = atomicAdd(&cursor[d], 1u);
            cedge[pos] = e;
        }
    }
}

// FUSED: wave per destination node: MFMA MLP on 16-edge tiles, online softmax,
// PV from the staged LDS tile, one compact output row per node.
__global__ __launch_bounds__(256) void fused_kernel(
    const float* __restrict__ embed_u, const float* __restrict__ rep,
    const float* __restrict__ W1, const float* __restrict__ b1,
    const float* __restrict__ W2, const float* __restrict__ b2,
    const float* __restrict__ W3,
    const unsigned* __restrict__ nflag_p,
    const int* __restrict__ nlist,
    const unsigned* __restrict__ csr_off, const unsigned* __restrict__ deg,
    const int* __restrict__ cedge,
    float* __restrict__ aggc)
{
    __shared__ __align__(16) short W1t[64 * 136];
    __shared__ __align__(16) short W2t[64 * 72];
    __shared__ __align__(16) short Xbf[4][16 * 136];
    __shared__ __align__(16) short Hs[4][16 * 72];
    __shared__ float scL[4][16];

    const int tid = threadIdx.x;
    for (int i = tid; i < 128 * 64; i += 256) {
        int k = i >> 6, c = i & 63;
        W1t[c * 136 + k] = (short)f2bf(W1[i]);
    }
    for (int i = tid; i < 64 * 64; i += 256) {
        int k = i >> 6, c = i & 63;
        W2t[c * 72 + k] = (short)f2bf(W2[i]);
    }
    __syncthreads();

    const int nflag = (int)*nflag_p;
    const int wid = tid >> 6;
    const int lane = tid & 63;
    const int cl = lane & 15;
    const int quad = lane >> 4;

    float b1v[4], b2v[4], w3v[4];
    #pragma unroll
    for (int ct = 0; ct < 4; ++ct) {
        b1v[ct] = b1[ct * 16 + cl];
        b2v[ct] = b2[ct * 16 + cl];
        w3v[ct] = W3[ct * 16 + cl];
    }

    short* Xw = Xbf[wid];
    short* Hw = Hs[wid];
    float* scl = scL[wid];

    const int gw = (blockIdx.x * 256 + tid) >> 6;
    const int nw = (gridDim.x * 256) >> 6;

    for (int ni = gw; ni < nflag; ni += nw) {
        const int n = nlist[ni];
        const int o = (int)csr_off[n];
        const int dn = (int)deg[n];
        const int ntile = (dn + 15) >> 4;

        float m = -INFINITY, S = 0.f, acc = 0.f;

        for (int t = 0; t < ntile; ++t) {
            const int rem = dn - t * 16;
            const int er = cedge[o + t * 16 + min(cl, rem - 1)];
            const float4* eb = (const float4*)(embed_u + (size_t)er * D);
            const float4* rp = (const float4*)(rep + (size_t)er * D);
            #pragma unroll
            for (int src = 0; src < 2; ++src) {
                const float4* pbase = src ? rp : eb;
                const int kofs = src ? 64 : 0;
                #pragma unroll
                for (int h = 0; h < 2; ++h) {
                    float4 v0 = pbase[quad * 4 + h * 2 + 0];
                    float4 v1 = pbase[quad * 4 + h * 2 + 1];
                    s16x8 pk;
                    pk[0] = (short)f2bf(v0.x); pk[1] = (short)f2bf(v0.y);
                    pk[2] = (short)f2bf(v0.z); pk[3] = (short)f2bf(v0.w);
                    pk[4] = (short)f2bf(v1.x); pk[5] = (short)f2bf(v1.y);
                    pk[6] = (short)f2bf(v1.z); pk[7] = (short)f2bf(v1.w);
                    *(s16x8*)&Xw[cl * 136 + kofs + quad * 16 + h * 8] = pk;
                }
            }

            // layer 1: [16,128] x [128,64]
            f32x4 a1[4];
            #pragma unroll
            for (int ct = 0; ct < 4; ++ct)
                a1[ct] = (f32x4){b1v[ct], b1v[ct], b1v[ct], b1v[ct]};
            #pragma unroll
            for (int ks = 0; ks < 4; ++ks) {
                s16x8 af = *(const s16x8*)&Xw[cl * 136 + ks * 32 + quad * 8];
                #pragma unroll
                for (int ct = 0; ct < 4; ++ct) {
                    s16x8 bf = *(const s16x8*)&W1t[(ct * 16 + cl) * 136 + ks * 32 + quad * 8];
                    a1[ct] = __builtin_amdgcn_mfma_f32_16x16x32_bf16(af, bf, a1[ct], 0, 0, 0);
                }
            }
            #pragma unroll
            for (int ct = 0; ct < 4; ++ct)
                #pragma unroll
                for (int reg = 0; reg < 4; ++reg)
                    Hw[(quad * 4 + reg) * 72 + ct * 16 + cl] =
                        (short)f2bf(fmaxf(a1[ct][reg], 0.f));

            // layer 2: [16,64] x [64,64]
            f32x4 a2[4];
            #pragma unroll
            for (int ct = 0; ct < 4; ++ct)
                a2[ct] = (f32x4){b2v[ct], b2v[ct], b2v[ct], b2v[ct]};
            #pragma unroll
            for (int ks = 0; ks < 2; ++ks) {
                s16x8 af = *(const s16x8*)&Hw[cl * 72 + ks * 32 + quad * 8];
                #pragma unroll
                for (int ct = 0; ct < 4; ++ct) {
                    s16x8 bf = *(const s16x8*)&W2t[(ct * 16 + cl) * 72 + ks * 32 + quad * 8];
                    a2[ct] = __builtin_amdgcn_mfma_f32_16x16x32_bf16(af, bf, a2[ct], 0, 0, 0);
                }
            }

            // layer 3: per-row dot with W3 (b3 cancels in softmax)
            float p[4];
            #pragma unroll
            for (int reg = 0; reg < 4; ++reg) {
                float s = 0.f;
                #pragma unroll
                for (int ct = 0; ct < 4; ++ct)
                    s += fmaxf(a2[ct][reg], 0.f) * w3v[ct];
                p[reg] = s;
            }
            #pragma unroll
            for (int off = 1; off < 16; off <<= 1)
                #pragma unroll
                for (int reg = 0; reg < 4; ++reg)
                    p[reg] += __shfl_xor(p[reg], off);

            if (cl == 0) {
                #pragma unroll
                for (int reg = 0; reg < 4; ++reg) {
                    int row = quad * 4 + reg;
                    scl[row] = (row < rem) ? p[reg] : -INFINITY;
                }
            }
            __builtin_amdgcn_wave_barrier();

            // online softmax update + PV from LDS u-columns (lane = channel)
            float sv[16];
            #pragma unroll
            for (int r = 0; r < 16; ++r) sv[r] = scl[r];
            float tm = sv[0];
            #pragma unroll
            for (int r = 1; r < 16; ++r) tm = fmaxf(tm, sv[r]);
            const float mN = fmaxf(m, tm);
            const float scale = __expf(m - mN);   // 0 when m == -inf
            S *= scale; acc *= scale;
            #pragma unroll
            for (int r = 0; r < 16; ++r) {
                float wgt = __expf(sv[r] - mN);   // 0 for masked rows
                S += wgt;
                acc = fmaf(wgt, bf2f((unsigned short)Xw[r * 136 + lane]), acc);
            }
            m = mN;
            __builtin_amdgcn_wave_barrier();
        }

        aggc[(size_t)ni * D + lane] = acc / S;
    }
}

// out[b] = aggc[nrank[nodes[b]]]  (sentinel -> zero row, covers deg-0 requested nodes)
__global__ void gather_out_kernel(const int* __restrict__ nodes,
                                  const unsigned* __restrict__ nrank,
                                  const float* __restrict__ aggc,
                                  float* __restrict__ out, int B) {
    int t = blockIdx.x * blockDim.x + threadIdx.x;
    int b = t >> 6, lane = t & 63;
    if (b >= B) return;
    unsigned r = nrank[nodes[b]];
    out[(size_t)b * D + lane] = (r == 0xFFFFFFFFu) ? 0.f : aggc[(size_t)r * D + lane];
}

extern "C" void kernel_launch(void* const* d_in, const int* in_sizes, int n_in,
                              void* d_out, int out_size, void* d_ws, size_t ws_size,
                              hipStream_t stream) {
    const float* embed_u = (const float*)d_in[0];
    const float* rep     = (const float*)d_in[1];
    const int*   dst     = (const int*)d_in[2];
    const int*   nodes   = (const int*)d_in[3];
    const float* W1      = (const float*)d_in[4];
    const float* b1      = (const float*)d_in[5];
    const float* W2      = (const float*)d_in[6];
    const float* b2      = (const float*)d_in[7];
    const float* W3      = (const float*)d_in[8];
    float* out = (float*)d_out;
    const int E = in_sizes[2];
    const int B = in_sizes[3];

    char* ws = (char*)d_ws;
    unsigned* slot    = (unsigned*)(ws + 0);         // [N]
    unsigned* deg     = (unsigned*)(ws + 400000);    // [N] contiguous after slot
    unsigned* csr_off = (unsigned*)(ws + 800000);    // [N]
    unsigned* cursor  = (unsigned*)(ws + 1200000);   // [N]
    unsigned* nrank   = (unsigned*)(ws + 1600000);   // [N]
    int*      nlist   = (int*)     (ws + 2000000);   // [N]
    unsigned* bsum    = (unsigned*)(ws + 2400000);   // [512]
    unsigned* bnz     = (unsigned*)(ws + 2402048);   // [512]
    unsigned* nflag   = (unsigned*)(ws + 2404096);   // [1]
    unsigned* barcnt  = (unsigned*)(ws + 2404352);   // [1] (256-aligned)
    int*      cedge   = (int*)     (ws + (size_t)4 * 1024 * 1024);  // [E]
    float*    aggc    = (float*)   (ws + (size_t)8 * 1024 * 1024);  // [B*D] max

    hipMemsetAsync(barcnt, 0, 256, stream);

    setup_kernel<<<NB_SETUP, 256, 0, stream>>>(nodes, dst, slot, deg, csr_off, cursor,
                                               nrank, nlist, bsum, bnz, nflag, cedge,
                                               barcnt, E, B);

    fused_kernel<<<768, 256, 0, stream>>>(embed_u, rep, W1, b1, W2, b2, W3,
                                          nflag, nlist, csr_off, deg, cedge, aggc);

    gather_out_kernel<<<(B * D + 255) / 256, 256, 0, stream>>>(nodes, nrank, aggc, out, B);
}

// Round 6
// 87.253 us; speedup vs baseline: 5.8060x; 5.8060x over previous
//
#include <hip/hip_runtime.h>
#include <math.h>

static constexpr int N_NODES = 100000;
static constexpr int D = 64;
static constexpr int CHUNKN = 512;                                // nodes per scan block
static constexpr int NBSC = (N_NODES + CHUNKN - 1) / CHUNKN;      // 196

typedef float  f32x4 __attribute__((ext_vector_type(4)));
typedef short  s16x8 __attribute__((ext_vector_type(8)));

__device__ __forceinline__ unsigned short f2bf(float f) {
    unsigned u = __float_as_uint(f);
    return (unsigned short)((u + 0x7FFFu + ((u >> 16) & 1u)) >> 16);
}
__device__ __forceinline__ float bf2f(unsigned short s) {
    return __uint_as_float(((unsigned)s) << 16);
}

// Pass 1: mark requested nodes (slot zeroed by memset; plain idempotent store).
__global__ void mark_nodes_kernel(const int* __restrict__ nodes,
                                  unsigned* __restrict__ slot, int B) {
    int b = blockIdx.x * blockDim.x + threadIdx.x;
    if (b < B) slot[nodes[b]] = 1u;
}

// Pass 2: deg[d] = flagged-edge count per dst. int4-vectorized over dst.
__global__ __launch_bounds__(256) void degcount_kernel(
    const int* __restrict__ dst, const unsigned* __restrict__ slot,
    unsigned* __restrict__ deg, int E) {
    int t = blockIdx.x * blockDim.x + threadIdx.x;
    int E4 = E >> 2;
    if (t < E4) {
        int4 d = ((const int4*)dst)[t];
        if (slot[d.x]) atomicAdd(&deg[d.x], 1u);
        if (slot[d.y]) atomicAdd(&deg[d.y], 1u);
        if (slot[d.z]) atomicAdd(&deg[d.z], 1u);
        if (slot[d.w]) atomicAdd(&deg[d.w], 1u);
    }
    if (t == 0)
        for (int e = E4 << 2; e < E; ++e) {
            int d = dst[e];
            if (slot[d]) atomicAdd(&deg[d], 1u);
        }
}

// Pass 3a: per-block sums over deg (edge total, nonzero-node count).
__global__ __launch_bounds__(256) void nodesum_kernel(
    const unsigned* __restrict__ deg,
    unsigned* __restrict__ bsum, unsigned* __restrict__ bnz, int N) {
    const int base = blockIdx.x * CHUNKN;
    unsigned s = 0, z = 0;
    for (int it = 0; it < CHUNKN; it += 256) {
        int i = base + it + threadIdx.x;
        if (i < N) { unsigned v = deg[i]; s += v; z += (v > 0) ? 1u : 0u; }
    }
    #pragma unroll
    for (int off = 32; off; off >>= 1) { s += __shfl_down(s, off); z += __shfl_down(z, off); }
    __shared__ unsigned ws[4], wz[4];
    if ((threadIdx.x & 63) == 0) { ws[threadIdx.x >> 6] = s; wz[threadIdx.x >> 6] = z; }
    __syncthreads();
    if (threadIdx.x == 0) {
        bsum[blockIdx.x] = ws[0] + ws[1] + ws[2] + ws[3];
        bnz[blockIdx.x]  = wz[0] + wz[1] + wz[2] + wz[3];
    }
}

// Pass 3b: CSR offsets + flagged-node list; each block recomputes its global
// prefix from the 196 block sums (no separate scan kernel).
__global__ __launch_bounds__(256) void csrfill_kernel(
    const unsigned* __restrict__ deg,
    const unsigned* __restrict__ bsum, const unsigned* __restrict__ bnz,
    unsigned* __restrict__ csr_off, unsigned* __restrict__ cursor,
    unsigned* __restrict__ nrank, int* __restrict__ nlist,
    unsigned* __restrict__ nflag, int N, int NB)
{
    const int tid = threadIdx.x;
    const int lane = tid & 63, w = tid >> 6;
    unsigned se = 0, szv = 0, tz = 0;
    for (int k = tid; k < NB; k += 256) {
        unsigned be = bsum[k], bz = bnz[k];
        tz += bz;
        if (k < (int)blockIdx.x) { se += be; szv += bz; }
    }
    #pragma unroll
    for (int off = 32; off; off >>= 1) {
        se  += __shfl_down(se, off);
        szv += __shfl_down(szv, off);
        tz  += __shfl_down(tz, off);
    }
    __shared__ unsigned rA[4], rB[4], rC[4];
    if (lane == 0) { rA[w] = se; rB[w] = szv; rC[w] = tz; }
    __syncthreads();
    if (blockIdx.x == 0 && tid == 0) *nflag = rC[0] + rC[1] + rC[2] + rC[3];
    __shared__ unsigned runE, runZ;
    if (tid == 0) { runE = rA[0] + rA[1] + rA[2] + rA[3]; runZ = rB[0] + rB[1] + rB[2] + rB[3]; }
    __syncthreads();

    const int base = blockIdx.x * CHUNKN;
    __shared__ unsigned wsE[4], wsZ[4];
    for (int it = 0; it < CHUNKN; it += 256) {
        int i = base + it + tid;
        unsigned v = (i < N) ? deg[i] : 0u;
        unsigned p = v;
        #pragma unroll
        for (int off = 1; off < 64; off <<= 1) {
            unsigned t2 = __shfl_up(p, off);
            if (lane >= off) p += t2;
        }
        bool nz = v > 0u;
        unsigned long long mb = __ballot(nz);
        unsigned lower = __popcll(mb & ((1ull << lane) - 1ull));
        if (lane == 63) { wsE[w] = p; wsZ[w] = (unsigned)__popcll(mb); }
        __syncthreads();
        unsigned woffE = 0, woffZ = 0;
        for (int ww = 0; ww < w; ++ww) { woffE += wsE[ww]; woffZ += wsZ[ww]; }
        if (i < N) {
            unsigned o = runE + woffE + p - v;
            csr_off[i] = o;
            cursor[i] = o;
            if (nz) { unsigned r = runZ + woffZ + lower; nlist[r] = i; nrank[i] = r; }
            else nrank[i] = 0xFFFFFFFFu;
        }
        __syncthreads();
        if (tid == 0) {
            runE += wsE[0] + wsE[1] + wsE[2] + wsE[3];
            runZ += wsZ[0] + wsZ[1] + wsZ[2] + wsZ[3];
        }
        __syncthreads();
    }
}

// Pass 4: scatter flagged edges into per-dst CSR lists. int4-vectorized.
__global__ __launch_bounds__(256) void scatter_kernel(
    const int* __restrict__ dst, const unsigned* __restrict__ slot,
    unsigned* __restrict__ cursor, int* __restrict__ cedge, int E) {
    int t = blockIdx.x * blockDim.x + threadIdx.x;
    int E4 = E >> 2;
    if (t < E4) {
        int4 d = ((const int4*)dst)[t];
        int e = t << 2;
        if (slot[d.x]) cedge[atomicAdd(&cursor[d.x], 1u)] = e;
        if (slot[d.y]) cedge[atomicAdd(&cursor[d.y], 1u)] = e + 1;
        if (slot[d.z]) cedge[atomicAdd(&cursor[d.z], 1u)] = e + 2;
        if (slot[d.w]) cedge[atomicAdd(&cursor[d.w], 1u)] = e + 3;
    }
    if (t == 0)
        for (int e = E4 << 2; e < E; ++e) {
            int d = dst[e];
            if (slot[d]) cedge[atomicAdd(&cursor[d], 1u)] = e;
        }
}

// Pass 5: FUSED — wave per destination node: MFMA MLP on 16-edge tiles,
// online softmax across tiles, PV from the staged LDS tile, compact row out.
__global__ __launch_bounds__(256) void fused_kernel(
    const float* __restrict__ embed_u, const float* __restrict__ rep,
    const float* __restrict__ W1, const float* __restrict__ b1,
    const float* __restrict__ W2, const float* __restrict__ b2,
    const float* __restrict__ W3,
    const unsigned* __restrict__ nflag_p,
    const int* __restrict__ nlist,
    const unsigned* __restrict__ csr_off, const unsigned* __restrict__ deg,
    const int* __restrict__ cedge,
    float* __restrict__ aggc)
{
    __shared__ __align__(16) short W1t[64 * 136];
    __shared__ __align__(16) short W2t[64 * 72];
    __shared__ __align__(16) short Xbf[4][16 * 136];
    __shared__ __align__(16) short Hs[4][16 * 72];
    __shared__ float scL[4][16];

    const int tid = threadIdx.x;
    for (int i = tid; i < 128 * 64; i += 256) {
        int k = i >> 6, c = i & 63;
        W1t[c * 136 + k] = (short)f2bf(W1[i]);
    }
    for (int i = tid; i < 64 * 64; i += 256) {
        int k = i >> 6, c = i & 63;
        W2t[c * 72 + k] = (short)f2bf(W2[i]);
    }
    __syncthreads();

    const int nflag = (int)*nflag_p;
    const int wid = tid >> 6;
    const int lane = tid & 63;
    const int cl = lane & 15;
    const int quad = lane >> 4;

    float b1v[4], b2v[4], w3v[4];
    #pragma unroll
    for (int ct = 0; ct < 4; ++ct) {
        b1v[ct] = b1[ct * 16 + cl];
        b2v[ct] = b2[ct * 16 + cl];
        w3v[ct] = W3[ct * 16 + cl];
    }

    short* Xw = Xbf[wid];
    short* Hw = Hs[wid];
    float* scl = scL[wid];

    const int gw = (blockIdx.x * 256 + tid) >> 6;
    const int nw = (gridDim.x * 256) >> 6;

    for (int ni = gw; ni < nflag; ni += nw) {
        const int n = nlist[ni];
        const int o = (int)csr_off[n];
        const int dn = (int)deg[n];
        const int ntile = (dn + 15) >> 4;

        float m = -INFINITY, S = 0.f, acc = 0.f;

        for (int t = 0; t < ntile; ++t) {
            const int rem = dn - t * 16;
            const int er = cedge[o + t * 16 + min(cl, rem - 1)];
            const float4* eb = (const float4*)(embed_u + (size_t)er * D);
            const float4* rp = (const float4*)(rep + (size_t)er * D);
            #pragma unroll
            for (int src = 0; src < 2; ++src) {
                const float4* pbase = src ? rp : eb;
                const int kofs = src ? 64 : 0;
                #pragma unroll
                for (int h = 0; h < 2; ++h) {
                    float4 v0 = pbase[quad * 4 + h * 2 + 0];
                    float4 v1 = pbase[quad * 4 + h * 2 + 1];
                    s16x8 pk;
                    pk[0] = (short)f2bf(v0.x); pk[1] = (short)f2bf(v0.y);
                    pk[2] = (short)f2bf(v0.z); pk[3] = (short)f2bf(v0.w);
                    pk[4] = (short)f2bf(v1.x); pk[5] = (short)f2bf(v1.y);
                    pk[6] = (short)f2bf(v1.z); pk[7] = (short)f2bf(v1.w);
                    *(s16x8*)&Xw[cl * 136 + kofs + quad * 16 + h * 8] = pk;
                }
            }

            // layer 1: [16,128] x [128,64]
            f32x4 a1[4];
            #pragma unroll
            for (int ct = 0; ct < 4; ++ct)
                a1[ct] = (f32x4){b1v[ct], b1v[ct], b1v[ct], b1v[ct]};
            #pragma unroll
            for (int ks = 0; ks < 4; ++ks) {
                s16x8 af = *(const s16x8*)&Xw[cl * 136 + ks * 32 + quad * 8];
                #pragma unroll
                for (int ct = 0; ct < 4; ++ct) {
                    s16x8 bf = *(const s16x8*)&W1t[(ct * 16 + cl) * 136 + ks * 32 + quad * 8];
                    a1[ct] = __builtin_amdgcn_mfma_f32_16x16x32_bf16(af, bf, a1[ct], 0, 0, 0);
                }
            }
            #pragma unroll
            for (int ct = 0; ct < 4; ++ct)
                #pragma unroll
                for (int reg = 0; reg < 4; ++reg)
                    Hw[(quad * 4 + reg) * 72 + ct * 16 + cl] =
                        (short)f2bf(fmaxf(a1[ct][reg], 0.f));

            // layer 2: [16,64] x [64,64]
            f32x4 a2[4];
            #pragma unroll
            for (int ct = 0; ct < 4; ++ct)
                a2[ct] = (f32x4){b2v[ct], b2v[ct], b2v[ct], b2v[ct]};
            #pragma unroll
            for (int ks = 0; ks < 2; ++ks) {
                s16x8 af = *(const s16x8*)&Hw[cl * 72 + ks * 32 + quad * 8];
                #pragma unroll
                for (int ct = 0; ct < 4; ++ct) {
                    s16x8 bf = *(const s16x8*)&W2t[(ct * 16 + cl) * 72 + ks * 32 + quad * 8];
                    a2[ct] = __builtin_amdgcn_mfma_f32_16x16x32_bf16(af, bf, a2[ct], 0, 0, 0);
                }
            }

            // layer 3: per-row dot with W3 (b3 cancels in softmax)
            float p[4];
            #pragma unroll
            for (int reg = 0; reg < 4; ++reg) {
                float s = 0.f;
                #pragma unroll
                for (int ct = 0; ct < 4; ++ct)
                    s += fmaxf(a2[ct][reg], 0.f) * w3v[ct];
                p[reg] = s;
            }
            #pragma unroll
            for (int off = 1; off < 16; off <<= 1)
                #pragma unroll
                for (int reg = 0; reg < 4; ++reg)
                    p[reg] += __shfl_xor(p[reg], off);

            if (cl == 0) {
                #pragma unroll
                for (int reg = 0; reg < 4; ++reg) {
                    int row = quad * 4 + reg;
                    scl[row] = (row < rem) ? p[reg] : -INFINITY;
                }
            }
            __builtin_amdgcn_wave_barrier();

            // online softmax update + PV from LDS u-columns (lane = channel)
            float sv[16];
            #pragma unroll
            for (int r = 0; r < 16; ++r) sv[r] = scl[r];
            float tm = sv[0];
            #pragma unroll
            for (int r = 1; r < 16; ++r) tm = fmaxf(tm, sv[r]);
            const float mN = fmaxf(m, tm);
            const float scale = __expf(m - mN);   // 0 when m == -inf
            S *= scale; acc *= scale;
            #pragma unroll
            for (int r = 0; r < 16; ++r) {
                float wgt = __expf(sv[r] - mN);   // 0 for masked rows
                S += wgt;
                acc = fmaf(wgt, bf2f((unsigned short)Xw[r * 136 + lane]), acc);
            }
            m = mN;
            __builtin_amdgcn_wave_barrier();
        }

        aggc[(size_t)ni * D + lane] = acc / S;
    }
}

// Pass 6: out[b] = aggc[nrank[nodes[b]]]  (sentinel -> zero row: deg-0 nodes)
__global__ void gather_out_kernel(const int* __restrict__ nodes,
                                  const unsigned* __restrict__ nrank,
                                  const float* __restrict__ aggc,
                                  float* __restrict__ out, int B) {
    int t = blockIdx.x * blockDim.x + threadIdx.x;
    int b = t >> 6, lane = t & 63;
    if (b >= B) return;
    unsigned r = nrank[nodes[b]];
    out[(size_t)b * D + lane] = (r == 0xFFFFFFFFu) ? 0.f : aggc[(size_t)r * D + lane];
}

extern "C" void kernel_launch(void* const* d_in, const int* in_sizes, int n_in,
                              void* d_out, int out_size, void* d_ws, size_t ws_size,
                              hipStream_t stream) {
    const float* embed_u = (const float*)d_in[0];
    const float* rep     = (const float*)d_in[1];
    const int*   dst     = (const int*)d_in[2];
    const int*   nodes   = (const int*)d_in[3];
    const float* W1      = (const float*)d_in[4];
    const float* b1      = (const float*)d_in[5];
    const float* W2      = (const float*)d_in[6];
    const float* b2      = (const float*)d_in[7];
    const float* W3      = (const float*)d_in[8];
    float* out = (float*)d_out;
    const int E = in_sizes[2];
    const int B = in_sizes[3];

    char* ws = (char*)d_ws;
    unsigned* slot    = (unsigned*)(ws + 0);         // [N]
    unsigned* deg     = (unsigned*)(ws + 400000);    // [N] (contiguous after slot)
    unsigned* csr_off = (unsigned*)(ws + 800000);    // [N]
    unsigned* cursor  = (unsigned*)(ws + 1200000);   // [N]
    unsigned* nrank   = (unsigned*)(ws + 1600000);   // [N]
    int*      nlist   = (int*)     (ws + 2000000);   // [N]
    unsigned* bsum    = (unsigned*)(ws + 2400000);   // [NBSC]
    unsigned* bnz     = (unsigned*)(ws + 2402048);   // [NBSC]
    unsigned* nflag   = (unsigned*)(ws + 2404096);   // [1]
    int*      cedge   = (int*)     (ws + (size_t)4 * 1024 * 1024);  // [E]
    float*    aggc    = (float*)   (ws + (size_t)8 * 1024 * 1024);  // [B*D] max

    // zero slot+deg with ONE fill (contiguous 800000 B)
    hipMemsetAsync(slot, 0, 800000, stream);

    mark_nodes_kernel<<<(B + 255) / 256, 256, 0, stream>>>(nodes, slot, B);

    degcount_kernel<<<((E >> 2) + 255) / 256, 256, 0, stream>>>(dst, slot, deg, E);

    nodesum_kernel<<<NBSC, 256, 0, stream>>>(deg, bsum, bnz, N_NODES);

    csrfill_kernel<<<NBSC, 256, 0, stream>>>(deg, bsum, bnz, csr_off, cursor,
                                             nrank, nlist, nflag, N_NODES, NBSC);

    scatter_kernel<<<((E >> 2) + 255) / 256, 256, 0, stream>>>(dst, slot, cursor, cedge, E);

    fused_kernel<<<512, 256, 0, stream>>>(embed_u, rep, W1, b1, W2, b2, W3,
                                          nflag, nlist, csr_off, deg, cedge, aggc);

    gather_out_kernel<<<(B * D + 255) / 256, 256, 0, stream>>>(nodes, nrank, aggc, out, B);
}

// Round 7
// 78.796 us; speedup vs baseline: 6.4292x; 1.1073x over previous
//
#include <hip/hip_runtime.h>
#include <math.h>

static constexpr int N_NODES = 100000;
static constexpr int D = 64;
static constexpr int CHUNKN = 512;                                // nodes per csrfill block
static constexpr int NBSC = (N_NODES + CHUNKN - 1) / CHUNKN;      // 196

typedef float  f32x4 __attribute__((ext_vector_type(4)));
typedef short  s16x8 __attribute__((ext_vector_type(8)));

__device__ __forceinline__ unsigned short f2bf(float f) {
    unsigned u = __float_as_uint(f);
    return (unsigned short)((u + 0x7FFFu + ((u >> 16) & 1u)) >> 16);
}
__device__ __forceinline__ float bf2f(unsigned short s) {
    return __uint_as_float(((unsigned)s) << 16);
}

// Pass 1: zero deg + counters, mark requested nodes.
// NOTE: slot is NEVER zeroed. slot[n]==1u means "requested". Stale garbage that
// happens to equal 1u only causes harmless extra work (unused aggc rows);
// gather reads only ranks of genuinely requested nodes. Marked entries persist
// across graph replays -> deterministic.
__global__ __launch_bounds__(256) void init_mark_kernel(
    const int* __restrict__ nodes, unsigned* __restrict__ slot,
    unsigned* __restrict__ deg, unsigned* __restrict__ counters, int B, int N) {
    int t = blockIdx.x * 256 + threadIdx.x;
    if (t < 2) counters[t] = 0u;
    if (t < N) deg[t] = 0u;
    if (t < B) slot[nodes[t]] = 1u;
}

// Pass 2: deg[d] = flagged-edge count per dst. int4-vectorized over dst.
__global__ __launch_bounds__(256) void degcount_kernel(
    const int* __restrict__ dst, const unsigned* __restrict__ slot,
    unsigned* __restrict__ deg, int E) {
    int t = blockIdx.x * blockDim.x + threadIdx.x;
    int E4 = E >> 2;
    if (t < E4) {
        int4 d = ((const int4*)dst)[t];
        if (slot[d.x] == 1u) atomicAdd(&deg[d.x], 1u);
        if (slot[d.y] == 1u) atomicAdd(&deg[d.y], 1u);
        if (slot[d.z] == 1u) atomicAdd(&deg[d.z], 1u);
        if (slot[d.w] == 1u) atomicAdd(&deg[d.w], 1u);
    }
    if (t == 0)
        for (int e = E4 << 2; e < E; ++e) {
            int d = dst[e];
            if (slot[d] == 1u) atomicAdd(&deg[d], 1u);
        }
}

// Pass 3: CSR offsets + flagged-node list. Each block scans its 512 nodes
// locally, then claims a global range with ONE atomicAdd per counter
// (196 blocks -> uncontended). counters[0]=edge base, counters[1]=rank count.
__global__ __launch_bounds__(256) void csrfill_kernel(
    const unsigned* __restrict__ deg, unsigned* __restrict__ counters,
    unsigned* __restrict__ csr_off, unsigned* __restrict__ cursor,
    unsigned* __restrict__ nrank, int* __restrict__ nlist, int N)
{
    const int tid = threadIdx.x;
    const int lane = tid & 63, w = tid >> 6;
    const int base = blockIdx.x * CHUNKN;
    __shared__ unsigned wsE[4], wsZ[4];

    unsigned v[2], ex[2], lz[2];
    bool nzf[2];
    unsigned sumE = 0, sumZ = 0;

    #pragma unroll
    for (int it = 0; it < 2; ++it) {
        int i = base + it * 256 + tid;
        unsigned vv = (i < N) ? deg[i] : 0u;
        unsigned p = vv;
        #pragma unroll
        for (int off = 1; off < 64; off <<= 1) {
            unsigned t2 = __shfl_up(p, off);
            if (lane >= off) p += t2;
        }
        bool z = vv > 0u;
        unsigned long long mb = __ballot(z);
        unsigned lower = __popcll(mb & ((1ull << lane) - 1ull));
        if (lane == 63) { wsE[w] = p; wsZ[w] = (unsigned)__popcll(mb); }
        __syncthreads();
        unsigned woffE = 0, woffZ = 0;
        for (int ww = 0; ww < w; ++ww) { woffE += wsE[ww]; woffZ += wsZ[ww]; }
        v[it] = vv; nzf[it] = z;
        ex[it] = sumE + woffE + p - vv;
        lz[it] = sumZ + woffZ + lower;
        sumE += wsE[0] + wsE[1] + wsE[2] + wsE[3];
        sumZ += wsZ[0] + wsZ[1] + wsZ[2] + wsZ[3];
        __syncthreads();
    }

    __shared__ unsigned baseE, baseZ;
    if (tid == 0) {
        baseE = atomicAdd(&counters[0], sumE);
        baseZ = atomicAdd(&counters[1], sumZ);
    }
    __syncthreads();

    #pragma unroll
    for (int it = 0; it < 2; ++it) {
        int i = base + it * 256 + tid;
        if (i < N) {
            unsigned o = baseE + ex[it];
            csr_off[i] = o;
            cursor[i] = o;
            if (nzf[it]) { unsigned r = baseZ + lz[it]; nlist[r] = i; nrank[i] = r; }
            else nrank[i] = 0xFFFFFFFFu;
        }
    }
}

// Pass 4: scatter flagged edges into per-dst CSR lists. int4-vectorized.
__global__ __launch_bounds__(256) void scatter_kernel(
    const int* __restrict__ dst, const unsigned* __restrict__ slot,
    unsigned* __restrict__ cursor, int* __restrict__ cedge, int E) {
    int t = blockIdx.x * blockDim.x + threadIdx.x;
    int E4 = E >> 2;
    if (t < E4) {
        int4 d = ((const int4*)dst)[t];
        int e = t << 2;
        if (slot[d.x] == 1u) cedge[atomicAdd(&cursor[d.x], 1u)] = e;
        if (slot[d.y] == 1u) cedge[atomicAdd(&cursor[d.y], 1u)] = e + 1;
        if (slot[d.z] == 1u) cedge[atomicAdd(&cursor[d.z], 1u)] = e + 2;
        if (slot[d.w] == 1u) cedge[atomicAdd(&cursor[d.w], 1u)] = e + 3;
    }
    if (t == 0)
        for (int e = E4 << 2; e < E; ++e) {
            int d = dst[e];
            if (slot[d] == 1u) cedge[atomicAdd(&cursor[d], 1u)] = e;
        }
}

// Pass 5: FUSED — wave per destination node: MFMA MLP on 16-edge tiles,
// online softmax across tiles, PV from the staged LDS tile, compact row out.
__global__ __launch_bounds__(256) void fused_kernel(
    const float* __restrict__ embed_u, const float* __restrict__ rep,
    const float* __restrict__ W1, const float* __restrict__ b1,
    const float* __restrict__ W2, const float* __restrict__ b2,
    const float* __restrict__ W3,
    const unsigned* __restrict__ nflag_p,
    const int* __restrict__ nlist,
    const unsigned* __restrict__ csr_off, const unsigned* __restrict__ deg,
    const int* __restrict__ cedge,
    float* __restrict__ aggc)
{
    __shared__ __align__(16) short W1t[64 * 136];
    __shared__ __align__(16) short W2t[64 * 72];
    __shared__ __align__(16) short Xbf[4][16 * 136];
    __shared__ __align__(16) short Hs[4][16 * 72];
    __shared__ float scL[4][16];

    const int tid = threadIdx.x;
    for (int i = tid; i < 128 * 64; i += 256) {
        int k = i >> 6, c = i & 63;
        W1t[c * 136 + k] = (short)f2bf(W1[i]);
    }
    for (int i = tid; i < 64 * 64; i += 256) {
        int k = i >> 6, c = i & 63;
        W2t[c * 72 + k] = (short)f2bf(W2[i]);
    }
    __syncthreads();

    const int nflag = (int)*nflag_p;
    const int wid = tid >> 6;
    const int lane = tid & 63;
    const int cl = lane & 15;
    const int quad = lane >> 4;

    float b1v[4], b2v[4], w3v[4];
    #pragma unroll
    for (int ct = 0; ct < 4; ++ct) {
        b1v[ct] = b1[ct * 16 + cl];
        b2v[ct] = b2[ct * 16 + cl];
        w3v[ct] = W3[ct * 16 + cl];
    }

    short* Xw = Xbf[wid];
    short* Hw = Hs[wid];
    float* scl = scL[wid];

    const int gw = (blockIdx.x * 256 + tid) >> 6;
    const int nw = (gridDim.x * 256) >> 6;

    for (int ni = gw; ni < nflag; ni += nw) {
        const int n = nlist[ni];
        const int o = (int)csr_off[n];
        const int dn = (int)deg[n];
        const int ntile = (dn + 15) >> 4;

        float m = -INFINITY, S = 0.f, acc = 0.f;

        for (int t = 0; t < ntile; ++t) {
            const int rem = dn - t * 16;
            const int er = cedge[o + t * 16 + min(cl, rem - 1)];
            const float4* eb = (const float4*)(embed_u + (size_t)er * D);
            const float4* rp = (const float4*)(rep + (size_t)er * D);
            #pragma unroll
            for (int src = 0; src < 2; ++src) {
                const float4* pbase = src ? rp : eb;
                const int kofs = src ? 64 : 0;
                #pragma unroll
                for (int h = 0; h < 2; ++h) {
                    float4 v0 = pbase[quad * 4 + h * 2 + 0];
                    float4 v1 = pbase[quad * 4 + h * 2 + 1];
                    s16x8 pk;
                    pk[0] = (short)f2bf(v0.x); pk[1] = (short)f2bf(v0.y);
                    pk[2] = (short)f2bf(v0.z); pk[3] = (short)f2bf(v0.w);
                    pk[4] = (short)f2bf(v1.x); pk[5] = (short)f2bf(v1.y);
                    pk[6] = (short)f2bf(v1.z); pk[7] = (short)f2bf(v1.w);
                    *(s16x8*)&Xw[cl * 136 + kofs + quad * 16 + h * 8] = pk;
                }
            }

            // layer 1: [16,128] x [128,64]
            f32x4 a1[4];
            #pragma unroll
            for (int ct = 0; ct < 4; ++ct)
                a1[ct] = (f32x4){b1v[ct], b1v[ct], b1v[ct], b1v[ct]};
            #pragma unroll
            for (int ks = 0; ks < 4; ++ks) {
                s16x8 af = *(const s16x8*)&Xw[cl * 136 + ks * 32 + quad * 8];
                #pragma unroll
                for (int ct = 0; ct < 4; ++ct) {
                    s16x8 bf = *(const s16x8*)&W1t[(ct * 16 + cl) * 136 + ks * 32 + quad * 8];
                    a1[ct] = __builtin_amdgcn_mfma_f32_16x16x32_bf16(af, bf, a1[ct], 0, 0, 0);
                }
            }
            #pragma unroll
            for (int ct = 0; ct < 4; ++ct)
                #pragma unroll
                for (int reg = 0; reg < 4; ++reg)
                    Hw[(quad * 4 + reg) * 72 + ct * 16 + cl] =
                        (short)f2bf(fmaxf(a1[ct][reg], 0.f));

            // layer 2: [16,64] x [64,64]
            f32x4 a2[4];
            #pragma unroll
            for (int ct = 0; ct < 4; ++ct)
                a2[ct] = (f32x4){b2v[ct], b2v[ct], b2v[ct], b2v[ct]};
            #pragma unroll
            for (int ks = 0; ks < 2; ++ks) {
                s16x8 af = *(const s16x8*)&Hw[cl * 72 + ks * 32 + quad * 8];
                #pragma unroll
                for (int ct = 0; ct < 4; ++ct) {
                    s16x8 bf = *(const s16x8*)&W2t[(ct * 16 + cl) * 72 + ks * 32 + quad * 8];
                    a2[ct] = __builtin_amdgcn_mfma_f32_16x16x32_bf16(af, bf, a2[ct], 0, 0, 0);
                }
            }

            // layer 3: per-row dot with W3 (b3 cancels in softmax)
            float p[4];
            #pragma unroll
            for (int reg = 0; reg < 4; ++reg) {
                float s = 0.f;
                #pragma unroll
                for (int ct = 0; ct < 4; ++ct)
                    s += fmaxf(a2[ct][reg], 0.f) * w3v[ct];
                p[reg] = s;
            }
            #pragma unroll
            for (int off = 1; off < 16; off <<= 1)
                #pragma unroll
                for (int reg = 0; reg < 4; ++reg)
                    p[reg] += __shfl_xor(p[reg], off);

            if (cl == 0) {
                #pragma unroll
                for (int reg = 0; reg < 4; ++reg) {
                    int row = quad * 4 + reg;
                    scl[row] = (row < rem) ? p[reg] : -INFINITY;
                }
            }
            __builtin_amdgcn_wave_barrier();

            // online softmax update + PV from LDS u-columns (lane = channel)
            float sv[16];
            #pragma unroll
            for (int r = 0; r < 16; ++r) sv[r] = scl[r];
            float tm = sv[0];
            #pragma unroll
            for (int r = 1; r < 16; ++r) tm = fmaxf(tm, sv[r]);
            const float mN = fmaxf(m, tm);
            const float scale = __expf(m - mN);   // 0 when m == -inf
            S *= scale; acc *= scale;
            #pragma unroll
            for (int r = 0; r < 16; ++r) {
                float wgt = __expf(sv[r] - mN);   // 0 for masked rows
                S += wgt;
                acc = fmaf(wgt, bf2f((unsigned short)Xw[r * 136 + lane]), acc);
            }
            m = mN;
            __builtin_amdgcn_wave_barrier();
        }

        aggc[(size_t)ni * D + lane] = acc / S;
    }
}

// Pass 6: out[b] = aggc[nrank[nodes[b]]]  (sentinel -> zero row: deg-0 nodes)
__global__ void gather_out_kernel(const int* __restrict__ nodes,
                                  const unsigned* __restrict__ nrank,
                                  const float* __restrict__ aggc,
                                  float* __restrict__ out, int B) {
    int t = blockIdx.x * blockDim.x + threadIdx.x;
    int b = t >> 6, lane = t & 63;
    if (b >= B) return;
    unsigned r = nrank[nodes[b]];
    out[(size_t)b * D + lane] = (r == 0xFFFFFFFFu) ? 0.f : aggc[(size_t)r * D + lane];
}

extern "C" void kernel_launch(void* const* d_in, const int* in_sizes, int n_in,
                              void* d_out, int out_size, void* d_ws, size_t ws_size,
                              hipStream_t stream) {
    const float* embed_u = (const float*)d_in[0];
    const float* rep     = (const float*)d_in[1];
    const int*   dst     = (const int*)d_in[2];
    const int*   nodes   = (const int*)d_in[3];
    const float* W1      = (const float*)d_in[4];
    const float* b1      = (const float*)d_in[5];
    const float* W2      = (const float*)d_in[6];
    const float* b2      = (const float*)d_in[7];
    const float* W3      = (const float*)d_in[8];
    float* out = (float*)d_out;
    const int E = in_sizes[2];
    const int B = in_sizes[3];

    char* ws = (char*)d_ws;
    unsigned* slot     = (unsigned*)(ws + 0);         // [N]  (never zeroed)
    unsigned* deg      = (unsigned*)(ws + 400000);    // [N]
    unsigned* csr_off  = (unsigned*)(ws + 800000);    // [N]
    unsigned* cursor   = (unsigned*)(ws + 1200000);   // [N]
    unsigned* nrank    = (unsigned*)(ws + 1600000);   // [N]
    int*      nlist    = (int*)     (ws + 2000000);   // [N]
    unsigned* counters = (unsigned*)(ws + 2400000);   // [0]=edge base, [1]=rank count
    int*      cedge    = (int*)     (ws + (size_t)4 * 1024 * 1024);  // [E]
    float*    aggc     = (float*)   (ws + (size_t)8 * 1024 * 1024);  // [N*D] worst case

    const int initThreads = (N_NODES > B ? N_NODES : B);

    init_mark_kernel<<<(initThreads + 255) / 256, 256, 0, stream>>>(
        nodes, slot, deg, counters, B, N_NODES);

    degcount_kernel<<<((E >> 2) + 255) / 256, 256, 0, stream>>>(dst, slot, deg, E);

    csrfill_kernel<<<NBSC, 256, 0, stream>>>(deg, counters, csr_off, cursor,
                                             nrank, nlist, N_NODES);

    scatter_kernel<<<((E >> 2) + 255) / 256, 256, 0, stream>>>(dst, slot, cursor, cedge, E);

    fused_kernel<<<768, 256, 0, stream>>>(embed_u, rep, W1, b1, W2, b2, W3,
                                          counters + 1, nlist, csr_off, deg, cedge, aggc);

    gather_out_kernel<<<(B * D + 255) / 256, 256, 0, stream>>>(nodes, nrank, aggc, out, B);
}

// Round 8
// 56.638 us; speedup vs baseline: 8.9443x; 1.3912x over previous
//
#include <hip/hip_runtime.h>
#include <math.h>

static constexpr int N_NODES = 100000;
static constexpr int D = 64;
static constexpr unsigned CAP = 64;    // bucket capacity per node (Poisson(10) max ~35)

typedef float  f32x4 __attribute__((ext_vector_type(4)));
typedef short  s16x8 __attribute__((ext_vector_type(8)));

__device__ __forceinline__ unsigned short f2bf(float f) {
    unsigned u = __float_as_uint(f);
    return (unsigned short)((u + 0x7FFFu + ((u >> 16) & 1u)) >> 16);
}
__device__ __forceinline__ float bf2f(unsigned short s) {
    return __uint_as_float(((unsigned)s) << 16);
}

// Pass 1: zero deg + overflow counter, mark requested nodes.
// slot is NEVER zeroed: slot[n]==1u means "requested". Stale garbage==1u only
// causes harmless unused bucket rows; fused reads buckets only for nodes[b].
// Marks persist across replays -> deterministic.
__global__ __launch_bounds__(256) void init_mark_kernel(
    const int* __restrict__ nodes, unsigned* __restrict__ slot,
    unsigned* __restrict__ deg, unsigned* __restrict__ ovfcnt, int B, int N) {
    int t = blockIdx.x * 256 + threadIdx.x;
    if (t == 0) *ovfcnt = 0u;
    if (t < N) deg[t] = 0u;
    if (t < B) slot[nodes[t]] = 1u;
}

// Pass 2: single pass over edges — count degree AND scatter into fixed-stride
// buckets (atomicAdd return = slot). Overflow (pos>=CAP) goes to a list with
// guaranteed capacity E (fully correct for any degree distribution).
__global__ __launch_bounds__(256) void bucket_kernel(
    const int* __restrict__ dst, const unsigned* __restrict__ slot,
    unsigned* __restrict__ deg, int* __restrict__ bucket,
    unsigned* __restrict__ ovfcnt, int* __restrict__ ovf, int E) {
    int t = blockIdx.x * blockDim.x + threadIdx.x;
    int E4 = E >> 2;
    auto proc = [&](int e, int d) {
        if (slot[d] == 1u) {
            unsigned pos = atomicAdd(&deg[d], 1u);
            if (pos < CAP) bucket[(size_t)d * CAP + pos] = e;
            else {
                unsigned oi = atomicAdd(ovfcnt, 1u);
                ovf[2 * oi] = e; ovf[2 * oi + 1] = d;
            }
        }
    };
    if (t < E4) {
        int4 d = ((const int4*)dst)[t];
        int e = t << 2;
        proc(e, d.x); proc(e + 1, d.y); proc(e + 2, d.z); proc(e + 3, d.w);
    }
    if (t == 0)
        for (int e = E4 << 2; e < E; ++e) proc(e, dst[e]);
}

// Pass 3: FUSED over the BATCH — wave per batch entry b: n=nodes[b], MFMA MLP
// on 16-edge tiles from bucket[n], online softmax, PV from the staged LDS
// tile, write out[b] directly. Duplicate nodes recompute (~8%), no races.
__global__ __launch_bounds__(256) void fused_kernel(
    const float* __restrict__ embed_u, const float* __restrict__ rep,
    const float* __restrict__ W1, const float* __restrict__ b1,
    const float* __restrict__ W2, const float* __restrict__ b2,
    const float* __restrict__ W3,
    const int* __restrict__ nodes,
    const unsigned* __restrict__ deg, const int* __restrict__ bucket,
    const unsigned* __restrict__ ovfcnt, const int* __restrict__ ovf,
    float* __restrict__ out, int B)
{
    __shared__ __align__(16) short W1t[64 * 136];
    __shared__ __align__(16) short W2t[64 * 72];
    __shared__ __align__(16) short Xbf[4][16 * 136];
    __shared__ __align__(16) short Hs[4][16 * 72];
    __shared__ float scL[4][16];

    const int tid = threadIdx.x;
    for (int i = tid; i < 128 * 64; i += 256) {
        int k = i >> 6, c = i & 63;
        W1t[c * 136 + k] = (short)f2bf(W1[i]);
    }
    for (int i = tid; i < 64 * 64; i += 256) {
        int k = i >> 6, c = i & 63;
        W2t[c * 72 + k] = (short)f2bf(W2[i]);
    }
    __syncthreads();

    const int wid = tid >> 6;
    const int lane = tid & 63;
    const int cl = lane & 15;
    const int quad = lane >> 4;

    float b1v[4], b2v[4], w3v[4];
    #pragma unroll
    for (int ct = 0; ct < 4; ++ct) {
        b1v[ct] = b1[ct * 16 + cl];
        b2v[ct] = b2[ct * 16 + cl];
        w3v[ct] = W3[ct * 16 + cl];
    }

    short* Xw = Xbf[wid];
    short* Hw = Hs[wid];
    float* scl = scL[wid];

    const int gw = (blockIdx.x * 256 + tid) >> 6;
    const int nw = (gridDim.x * 256) >> 6;

    for (int ni = gw; ni < B; ni += nw) {
        const int n = nodes[ni];
        const int dn = (int)deg[n];

        float m = -INFINITY, S = 0.f, acc = 0.f;

        // one 16-edge MFMA tile: er = this lane-group's edge id, rem = valid rows
        auto do_tile = [&](int er, int rem) {
            const float4* eb = (const float4*)(embed_u + (size_t)er * D);
            const float4* rp = (const float4*)(rep + (size_t)er * D);
            #pragma unroll
            for (int src = 0; src < 2; ++src) {
                const float4* pbase = src ? rp : eb;
                const int kofs = src ? 64 : 0;
                #pragma unroll
                for (int h = 0; h < 2; ++h) {
                    float4 v0 = pbase[quad * 4 + h * 2 + 0];
                    float4 v1 = pbase[quad * 4 + h * 2 + 1];
                    s16x8 pk;
                    pk[0] = (short)f2bf(v0.x); pk[1] = (short)f2bf(v0.y);
                    pk[2] = (short)f2bf(v0.z); pk[3] = (short)f2bf(v0.w);
                    pk[4] = (short)f2bf(v1.x); pk[5] = (short)f2bf(v1.y);
                    pk[6] = (short)f2bf(v1.z); pk[7] = (short)f2bf(v1.w);
                    *(s16x8*)&Xw[cl * 136 + kofs + quad * 16 + h * 8] = pk;
                }
            }

            // layer 1: [16,128] x [128,64]
            f32x4 a1[4];
            #pragma unroll
            for (int ct = 0; ct < 4; ++ct)
                a1[ct] = (f32x4){b1v[ct], b1v[ct], b1v[ct], b1v[ct]};
            #pragma unroll
            for (int ks = 0; ks < 4; ++ks) {
                s16x8 af = *(const s16x8*)&Xw[cl * 136 + ks * 32 + quad * 8];
                #pragma unroll
                for (int ct = 0; ct < 4; ++ct) {
                    s16x8 bf = *(const s16x8*)&W1t[(ct * 16 + cl) * 136 + ks * 32 + quad * 8];
                    a1[ct] = __builtin_amdgcn_mfma_f32_16x16x32_bf16(af, bf, a1[ct], 0, 0, 0);
                }
            }
            #pragma unroll
            for (int ct = 0; ct < 4; ++ct)
                #pragma unroll
                for (int reg = 0; reg < 4; ++reg)
                    Hw[(quad * 4 + reg) * 72 + ct * 16 + cl] =
                        (short)f2bf(fmaxf(a1[ct][reg], 0.f));

            // layer 2: [16,64] x [64,64]
            f32x4 a2[4];
            #pragma unroll
            for (int ct = 0; ct < 4; ++ct)
                a2[ct] = (f32x4){b2v[ct], b2v[ct], b2v[ct], b2v[ct]};
            #pragma unroll
            for (int ks = 0; ks < 2; ++ks) {
                s16x8 af = *(const s16x8*)&Hw[cl * 72 + ks * 32 + quad * 8];
                #pragma unroll
                for (int ct = 0; ct < 4; ++ct) {
                    s16x8 bf = *(const s16x8*)&W2t[(ct * 16 + cl) * 72 + ks * 32 + quad * 8];
                    a2[ct] = __builtin_amdgcn_mfma_f32_16x16x32_bf16(af, bf, a2[ct], 0, 0, 0);
                }
            }

            // layer 3: per-row dot with W3 (b3 cancels in softmax)
            float p[4];
            #pragma unroll
            for (int reg = 0; reg < 4; ++reg) {
                float s = 0.f;
                #pragma unroll
                for (int ct = 0; ct < 4; ++ct)
                    s += fmaxf(a2[ct][reg], 0.f) * w3v[ct];
                p[reg] = s;
            }
            #pragma unroll
            for (int off = 1; off < 16; off <<= 1)
                #pragma unroll
                for (int reg = 0; reg < 4; ++reg)
                    p[reg] += __shfl_xor(p[reg], off);

            if (cl == 0) {
                #pragma unroll
                for (int reg = 0; reg < 4; ++reg) {
                    int row = quad * 4 + reg;
                    scl[row] = (row < rem) ? p[reg] : -INFINITY;
                }
            }
            __builtin_amdgcn_wave_barrier();

            // online softmax update + PV from LDS u-columns (lane = channel)
            float sv[16];
            #pragma unroll
            for (int r = 0; r < 16; ++r) sv[r] = scl[r];
            float tm = sv[0];
            #pragma unroll
            for (int r = 1; r < 16; ++r) tm = fmaxf(tm, sv[r]);
            const float mN = fmaxf(m, tm);
            const float scale = __expf(m - mN);   // 0 when m == -inf
            S *= scale; acc *= scale;
            #pragma unroll
            for (int r = 0; r < 16; ++r) {
                float wgt = __expf(sv[r] - mN);   // 0 for masked rows
                S += wgt;
                acc = fmaf(wgt, bf2f((unsigned short)Xw[r * 136 + lane]), acc);
            }
            m = mN;
            __builtin_amdgcn_wave_barrier();
        };

        const int nb = dn < (int)CAP ? dn : (int)CAP;
        const int ntile = (nb + 15) >> 4;
        for (int t = 0; t < ntile; ++t) {
            const int rem = nb - t * 16;
            const int er = bucket[(size_t)n * CAP + t * 16 + min(cl, rem - 1)];
            do_tile(er, rem);
        }
        if (dn > (int)CAP) {                      // guaranteed-correct slow path
            const int novf = (int)*ovfcnt;        // (expected 0 iterations)
            for (int i = 0; i < novf; ++i)
                if (ovf[2 * i + 1] == n) do_tile(ovf[2 * i], 1);
        }

        out[(size_t)ni * D + lane] = (dn > 0) ? acc / S : 0.f;
    }
}

extern "C" void kernel_launch(void* const* d_in, const int* in_sizes, int n_in,
                              void* d_out, int out_size, void* d_ws, size_t ws_size,
                              hipStream_t stream) {
    const float* embed_u = (const float*)d_in[0];
    const float* rep     = (const float*)d_in[1];
    const int*   dst     = (const int*)d_in[2];
    const int*   nodes   = (const int*)d_in[3];
    const float* W1      = (const float*)d_in[4];
    const float* b1      = (const float*)d_in[5];
    const float* W2      = (const float*)d_in[6];
    const float* b2      = (const float*)d_in[7];
    const float* W3      = (const float*)d_in[8];
    float* out = (float*)d_out;
    const int E = in_sizes[2];
    const int B = in_sizes[3];

    char* ws = (char*)d_ws;
    unsigned* slot   = (unsigned*)(ws + 0);                         // [N] never zeroed
    unsigned* deg    = (unsigned*)(ws + 400000);                    // [N]
    unsigned* ovfcnt = (unsigned*)(ws + 800000);                    // [1]
    int*      ovf    = (int*)     (ws + 1024 * 1024);               // [E*2] worst case
    int*      bucket = (int*)     (ws + (size_t)12 * 1024 * 1024);  // [N*CAP] = 25.6 MB

    const int initThreads = (N_NODES > B ? N_NODES : B);

    init_mark_kernel<<<(initThreads + 255) / 256, 256, 0, stream>>>(
        nodes, slot, deg, ovfcnt, B, N_NODES);

    bucket_kernel<<<((E >> 2) + 255) / 256, 256, 0, stream>>>(
        dst, slot, deg, bucket, ovfcnt, ovf, E);

    fused_kernel<<<768, 256, 0, stream>>>(embed_u, rep, W1, b1, W2, b2, W3,
                                          nodes, deg, bucket, ovfcnt, ovf, out, B);
}

// Round 9
// 51.243 us; speedup vs baseline: 9.8860x; 1.1053x over previous
//
#include <hip/hip_runtime.h>
#include <math.h>

static constexpr int N_NODES = 100000;
static constexpr int D = 64;
static constexpr unsigned CAP = 64;    // bucket capacity per node (Poisson(10) max ~35)

typedef float  f32x4 __attribute__((ext_vector_type(4)));
typedef short  s16x8 __attribute__((ext_vector_type(8)));

__device__ __forceinline__ unsigned short f2bf(float f) {
    unsigned u = __float_as_uint(f);
    return (unsigned short)((u + 0x7FFFu + ((u >> 16) & 1u)) >> 16);
}
__device__ __forceinline__ float bf2f(unsigned short s) {
    return __uint_as_float(((unsigned)s) << 16);
}

// Pass 1: zero deg + overflow counter, mark requested nodes.
// slot is NEVER zeroed: slot[n]==1u means "requested". Stale garbage==1u only
// causes harmless unused bucket rows; fused reads buckets only for nodes[b].
// Marks persist across replays -> deterministic.
__global__ __launch_bounds__(256) void init_mark_kernel(
    const int* __restrict__ nodes, unsigned* __restrict__ slot,
    unsigned* __restrict__ deg, unsigned* __restrict__ ovfcnt, int B, int N) {
    int t = blockIdx.x * 256 + threadIdx.x;
    if (t == 0) *ovfcnt = 0u;
    if (t < N) deg[t] = 0u;
    if (t < B) slot[nodes[t]] = 1u;
}

// Pass 2: single pass over edges — count degree AND scatter into fixed-stride
// buckets (atomicAdd return = slot). Overflow (pos>=CAP) goes to a list with
// guaranteed capacity E (fully correct for any degree distribution).
__global__ __launch_bounds__(256) void bucket_kernel(
    const int* __restrict__ dst, const unsigned* __restrict__ slot,
    unsigned* __restrict__ deg, int* __restrict__ bucket,
    unsigned* __restrict__ ovfcnt, int* __restrict__ ovf, int E) {
    int t = blockIdx.x * blockDim.x + threadIdx.x;
    int E4 = E >> 2;
    auto proc = [&](int e, int d) {
        if (slot[d] == 1u) {
            unsigned pos = atomicAdd(&deg[d], 1u);
            if (pos < CAP) bucket[(size_t)d * CAP + pos] = e;
            else {
                unsigned oi = atomicAdd(ovfcnt, 1u);
                ovf[2 * oi] = e; ovf[2 * oi + 1] = d;
            }
        }
    };
    if (t < E4) {
        int4 d = ((const int4*)dst)[t];
        int e = t << 2;
        proc(e, d.x); proc(e + 1, d.y); proc(e + 2, d.z); proc(e + 3, d.w);
    }
    if (t == 0)
        for (int e = E4 << 2; e < E; ++e) proc(e, dst[e]);
}

// Pass 3: FUSED over the BATCH — wave per batch entry b: n=nodes[b], MFMA MLP
// on 16-edge tiles from bucket[n], online softmax, PV from the staged LDS
// tile, write out[b] directly. 512-thread blocks (8 waves) share one W copy:
// LDS ~78.5 KB/block -> 2 blocks/CU = 16 waves/CU TLP for the row gathers.
__global__ __launch_bounds__(512) void fused_kernel(
    const float* __restrict__ embed_u, const float* __restrict__ rep,
    const float* __restrict__ W1, const float* __restrict__ b1,
    const float* __restrict__ W2, const float* __restrict__ b2,
    const float* __restrict__ W3,
    const int* __restrict__ nodes,
    const unsigned* __restrict__ deg, const int* __restrict__ bucket,
    const unsigned* __restrict__ ovfcnt, const int* __restrict__ ovf,
    float* __restrict__ out, int B)
{
    __shared__ __align__(16) short W1t[64 * 136];
    __shared__ __align__(16) short W2t[64 * 72];
    __shared__ __align__(16) short Xbf[8][16 * 136];
    __shared__ __align__(16) short Hs[8][16 * 72];
    __shared__ float scL[8][16];

    const int tid = threadIdx.x;
    for (int i = tid; i < 128 * 64; i += 512) {
        int k = i >> 6, c = i & 63;
        W1t[c * 136 + k] = (short)f2bf(W1[i]);
    }
    for (int i = tid; i < 64 * 64; i += 512) {
        int k = i >> 6, c = i & 63;
        W2t[c * 72 + k] = (short)f2bf(W2[i]);
    }
    __syncthreads();

    const int wid = tid >> 6;
    const int lane = tid & 63;
    const int cl = lane & 15;
    const int quad = lane >> 4;

    float b1v[4], b2v[4], w3v[4];
    #pragma unroll
    for (int ct = 0; ct < 4; ++ct) {
        b1v[ct] = b1[ct * 16 + cl];
        b2v[ct] = b2[ct * 16 + cl];
        w3v[ct] = W3[ct * 16 + cl];
    }

    short* Xw = Xbf[wid];
    short* Hw = Hs[wid];
    float* scl = scL[wid];

    const int gw = (blockIdx.x * 512 + tid) >> 6;
    const int nw = (gridDim.x * 512) >> 6;

    for (int ni = gw; ni < B; ni += nw) {
        const int n = nodes[ni];
        const int dn = (int)deg[n];

        float m = -INFINITY, S = 0.f, acc = 0.f;

        // one 16-edge MFMA tile: er = this lane-group's edge id, rem = valid rows
        auto do_tile = [&](int er, int rem) {
            const float4* eb = (const float4*)(embed_u + (size_t)er * D);
            const float4* rp = (const float4*)(rep + (size_t)er * D);
            #pragma unroll
            for (int src = 0; src < 2; ++src) {
                const float4* pbase = src ? rp : eb;
                const int kofs = src ? 64 : 0;
                #pragma unroll
                for (int h = 0; h < 2; ++h) {
                    float4 v0 = pbase[quad * 4 + h * 2 + 0];
                    float4 v1 = pbase[quad * 4 + h * 2 + 1];
                    s16x8 pk;
                    pk[0] = (short)f2bf(v0.x); pk[1] = (short)f2bf(v0.y);
                    pk[2] = (short)f2bf(v0.z); pk[3] = (short)f2bf(v0.w);
                    pk[4] = (short)f2bf(v1.x); pk[5] = (short)f2bf(v1.y);
                    pk[6] = (short)f2bf(v1.z); pk[7] = (short)f2bf(v1.w);
                    *(s16x8*)&Xw[cl * 136 + kofs + quad * 16 + h * 8] = pk;
                }
            }

            // layer 1: [16,128] x [128,64]
            f32x4 a1[4];
            #pragma unroll
            for (int ct = 0; ct < 4; ++ct)
                a1[ct] = (f32x4){b1v[ct], b1v[ct], b1v[ct], b1v[ct]};
            #pragma unroll
            for (int ks = 0; ks < 4; ++ks) {
                s16x8 af = *(const s16x8*)&Xw[cl * 136 + ks * 32 + quad * 8];
                #pragma unroll
                for (int ct = 0; ct < 4; ++ct) {
                    s16x8 bf = *(const s16x8*)&W1t[(ct * 16 + cl) * 136 + ks * 32 + quad * 8];
                    a1[ct] = __builtin_amdgcn_mfma_f32_16x16x32_bf16(af, bf, a1[ct], 0, 0, 0);
                }
            }
            #pragma unroll
            for (int ct = 0; ct < 4; ++ct)
                #pragma unroll
                for (int reg = 0; reg < 4; ++reg)
                    Hw[(quad * 4 + reg) * 72 + ct * 16 + cl] =
                        (short)f2bf(fmaxf(a1[ct][reg], 0.f));

            // layer 2: [16,64] x [64,64]
            f32x4 a2[4];
            #pragma unroll
            for (int ct = 0; ct < 4; ++ct)
                a2[ct] = (f32x4){b2v[ct], b2v[ct], b2v[ct], b2v[ct]};
            #pragma unroll
            for (int ks = 0; ks < 2; ++ks) {
                s16x8 af = *(const s16x8*)&Hw[cl * 72 + ks * 32 + quad * 8];
                #pragma unroll
                for (int ct = 0; ct < 4; ++ct) {
                    s16x8 bf = *(const s16x8*)&W2t[(ct * 16 + cl) * 72 + ks * 32 + quad * 8];
                    a2[ct] = __builtin_amdgcn_mfma_f32_16x16x32_bf16(af, bf, a2[ct], 0, 0, 0);
                }
            }

            // layer 3: per-row dot with W3 (b3 cancels in softmax)
            float p[4];
            #pragma unroll
            for (int reg = 0; reg < 4; ++reg) {
                float s = 0.f;
                #pragma unroll
                for (int ct = 0; ct < 4; ++ct)
                    s += fmaxf(a2[ct][reg], 0.f) * w3v[ct];
                p[reg] = s;
            }
            #pragma unroll
            for (int off = 1; off < 16; off <<= 1)
                #pragma unroll
                for (int reg = 0; reg < 4; ++reg)
                    p[reg] += __shfl_xor(p[reg], off);

            if (cl == 0) {
                #pragma unroll
                for (int reg = 0; reg < 4; ++reg) {
                    int row = quad * 4 + reg;
                    scl[row] = (row < rem) ? p[reg] : -INFINITY;
                }
            }
            __builtin_amdgcn_wave_barrier();

            // online softmax update + PV from LDS u-columns (lane = channel)
            float sv[16];
            #pragma unroll
            for (int r = 0; r < 16; ++r) sv[r] = scl[r];
            float tm = sv[0];
            #pragma unroll
            for (int r = 1; r < 16; ++r) tm = fmaxf(tm, sv[r]);
            const float mN = fmaxf(m, tm);
            const float scale = __expf(m - mN);   // 0 when m == -inf
            S *= scale; acc *= scale;
            #pragma unroll
            for (int r = 0; r < 16; ++r) {
                float wgt = __expf(sv[r] - mN);   // 0 for masked rows
                S += wgt;
                acc = fmaf(wgt, bf2f((unsigned short)Xw[r * 136 + lane]), acc);
            }
            m = mN;
            __builtin_amdgcn_wave_barrier();
        };

        const int nb = dn < (int)CAP ? dn : (int)CAP;
        const int ntile = (nb + 15) >> 4;
        for (int t = 0; t < ntile; ++t) {
            const int rem = nb - t * 16;
            const int er = bucket[(size_t)n * CAP + t * 16 + min(cl, rem - 1)];
            do_tile(er, rem);
        }
        if (dn > (int)CAP) {                      // guaranteed-correct slow path
            const int novf = (int)*ovfcnt;        // (expected 0 iterations)
            for (int i = 0; i < novf; ++i)
                if (ovf[2 * i + 1] == n) do_tile(ovf[2 * i], 1);
        }

        out[(size_t)ni * D + lane] = (dn > 0) ? acc / S : 0.f;
    }
}

extern "C" void kernel_launch(void* const* d_in, const int* in_sizes, int n_in,
                              void* d_out, int out_size, void* d_ws, size_t ws_size,
                              hipStream_t stream) {
    const float* embed_u = (const float*)d_in[0];
    const float* rep     = (const float*)d_in[1];
    const int*   dst     = (const int*)d_in[2];
    const int*   nodes   = (const int*)d_in[3];
    const float* W1      = (const float*)d_in[4];
    const float* b1      = (const float*)d_in[5];
    const float* W2      = (const float*)d_in[6];
    const float* b2      = (const float*)d_in[7];
    const float* W3      = (const float*)d_in[8];
    float* out = (float*)d_out;
    const int E = in_sizes[2];
    const int B = in_sizes[3];

    char* ws = (char*)d_ws;
    unsigned* slot   = (unsigned*)(ws + 0);                         // [N] never zeroed
    unsigned* deg    = (unsigned*)(ws + 400000);                    // [N]
    unsigned* ovfcnt = (unsigned*)(ws + 800000);                    // [1]
    int*      ovf    = (int*)     (ws + 1024 * 1024);               // [E*2] worst case
    int*      bucket = (int*)     (ws + (size_t)12 * 1024 * 1024);  // [N*CAP] = 25.6 MB

    const int initThreads = (N_NODES > B ? N_NODES : B);

    init_mark_kernel<<<(initThreads + 255) / 256, 256, 0, stream>>>(
        nodes, slot, deg, ovfcnt, B, N_NODES);

    bucket_kernel<<<((E >> 2) + 255) / 256, 256, 0, stream>>>(
        dst, slot, deg, bucket, ovfcnt, ovf, E);

    fused_kernel<<<512, 512, 0, stream>>>(embed_u, rep, W1, b1, W2, b2, W3,
                                          nodes, deg, bucket, ovfcnt, ovf, out, B);
}

// Round 10
// 49.691 us; speedup vs baseline: 10.1948x; 1.0312x over previous
//
#include <hip/hip_runtime.h>
#include <hip/hip_bf16.h>
#include <math.h>

static constexpr int N_NODES = 100000;
static constexpr int D = 64;
static constexpr unsigned CAP = 64;    // bucket capacity per node (Poisson(10) max ~35)

typedef float  f32x4 __attribute__((ext_vector_type(4)));
typedef short  s16x8 __attribute__((ext_vector_type(8)));

__device__ __forceinline__ unsigned short f2bf(float f) {
    __hip_bfloat16 h = __float2bfloat16(f);   // HW RNE; compiler fuses to v_cvt_pk_bf16_f32
    unsigned short u; __builtin_memcpy(&u, &h, 2); return u;
}
__device__ __forceinline__ float bf2f(unsigned short s) {
    return __uint_as_float(((unsigned)s) << 16);
}

// Pass 1: zero deg + overflow counter, mark requested nodes.
// slot is NEVER zeroed: slot[n]==1u means "requested". Stale garbage==1u only
// causes harmless unused bucket rows; fused reads buckets only for nodes[b].
// Marks persist across replays -> deterministic.
__global__ __launch_bounds__(256) void init_mark_kernel(
    const int* __restrict__ nodes, unsigned* __restrict__ slot,
    unsigned* __restrict__ deg, unsigned* __restrict__ ovfcnt, int B, int N) {
    int t = blockIdx.x * 256 + threadIdx.x;
    if (t == 0) *ovfcnt = 0u;
    if (t < N) deg[t] = 0u;
    if (t < B) slot[nodes[t]] = 1u;
}

// Pass 2: single pass over edges — count degree AND scatter into fixed-stride
// buckets (atomicAdd return = slot). Overflow (pos>=CAP) goes to a list with
// guaranteed capacity E (fully correct for any degree distribution).
__global__ __launch_bounds__(256) void bucket_kernel(
    const int* __restrict__ dst, const unsigned* __restrict__ slot,
    unsigned* __restrict__ deg, int* __restrict__ bucket,
    unsigned* __restrict__ ovfcnt, int* __restrict__ ovf, int E) {
    int t = blockIdx.x * blockDim.x + threadIdx.x;
    int E4 = E >> 2;
    auto proc = [&](int e, int d) {
        if (slot[d] == 1u) {
            unsigned pos = atomicAdd(&deg[d], 1u);
            if (pos < CAP) bucket[(size_t)d * CAP + pos] = e;
            else {
                unsigned oi = atomicAdd(ovfcnt, 1u);
                ovf[2 * oi] = e; ovf[2 * oi + 1] = d;
            }
        }
    };
    if (t < E4) {
        int4 d = ((const int4*)dst)[t];
        int e = t << 2;
        proc(e, d.x); proc(e + 1, d.y); proc(e + 2, d.z); proc(e + 3, d.w);
    }
    if (t == 0)
        for (int e = E4 << 2; e < E; ++e) proc(e, dst[e]);
}

// Pass 3: FUSED over the BATCH — wave per batch entry b: n=nodes[b], MFMA MLP
// on 16-edge tiles from bucket[n], online softmax, PV from the staged LDS
// tile, write out[b] directly. 512-thread blocks (8 waves) share one W copy
// (2 blocks/CU = 16 waves/CU). Next entry's n/deg/bucket-id dependent chain
// is prefetched while the current entry computes.
__global__ __launch_bounds__(512) void fused_kernel(
    const float* __restrict__ embed_u, const float* __restrict__ rep,
    const float* __restrict__ W1, const float* __restrict__ b1,
    const float* __restrict__ W2, const float* __restrict__ b2,
    const float* __restrict__ W3,
    const int* __restrict__ nodes,
    const unsigned* __restrict__ deg, const int* __restrict__ bucket,
    const unsigned* __restrict__ ovfcnt, const int* __restrict__ ovf,
    float* __restrict__ out, int B)
{
    __shared__ __align__(16) short W1t[64 * 136];
    __shared__ __align__(16) short W2t[64 * 72];
    __shared__ __align__(16) short Xbf[8][16 * 136];
    __shared__ __align__(16) short Hs[8][16 * 72];
    __shared__ float scL[8][16];

    const int tid = threadIdx.x;
    for (int i = tid; i < 128 * 64; i += 512) {
        int k = i >> 6, c = i & 63;
        W1t[c * 136 + k] = (short)f2bf(W1[i]);
    }
    for (int i = tid; i < 64 * 64; i += 512) {
        int k = i >> 6, c = i & 63;
        W2t[c * 72 + k] = (short)f2bf(W2[i]);
    }
    __syncthreads();

    const int wid = tid >> 6;
    const int lane = tid & 63;
    const int cl = lane & 15;
    const int quad = lane >> 4;

    float b1v[4], b2v[4], w3v[4];
    #pragma unroll
    for (int ct = 0; ct < 4; ++ct) {
        b1v[ct] = b1[ct * 16 + cl];
        b2v[ct] = b2[ct * 16 + cl];
        w3v[ct] = W3[ct * 16 + cl];
    }

    short* Xw = Xbf[wid];
    short* Hw = Hs[wid];
    float* scl = scL[wid];

    const int gw = (blockIdx.x * 512 + tid) >> 6;
    const int nw = (gridDim.x * 512) >> 6;

    // ---- prefetched metadata chain for the upcoming entry ----
    int n = 0, dn = 0, eraw = 0;
    if (gw < B) {
        n = nodes[gw];
        dn = (int)deg[n];
        eraw = bucket[(size_t)n * CAP + cl];   // tile-0 ids (lanes cl; in-bounds even if stale)
    }

    for (int ni = gw; ni < B; ni += nw) {
        const int curN = n, curDn = dn, curEraw = eraw;
        const int nx = ni + nw;
        if (nx < B) {                           // issue next chain early; overlaps compute
            n = nodes[nx];
            dn = (int)deg[n];
            eraw = bucket[(size_t)n * CAP + cl];
        }

        float m = -INFINITY, S = 0.f, acc = 0.f;

        // one 16-edge MFMA tile: er = this lane-group's edge id, rem = valid rows
        auto do_tile = [&](int er, int rem) {
            const float4* eb = (const float4*)(embed_u + (size_t)er * D);
            const float4* rp = (const float4*)(rep + (size_t)er * D);
            #pragma unroll
            for (int src = 0; src < 2; ++src) {
                const float4* pbase = src ? rp : eb;
                const int kofs = src ? 64 : 0;
                #pragma unroll
                for (int h = 0; h < 2; ++h) {
                    float4 v0 = pbase[quad * 4 + h * 2 + 0];
                    float4 v1 = pbase[quad * 4 + h * 2 + 1];
                    s16x8 pk;
                    pk[0] = (short)f2bf(v0.x); pk[1] = (short)f2bf(v0.y);
                    pk[2] = (short)f2bf(v0.z); pk[3] = (short)f2bf(v0.w);
                    pk[4] = (short)f2bf(v1.x); pk[5] = (short)f2bf(v1.y);
                    pk[6] = (short)f2bf(v1.z); pk[7] = (short)f2bf(v1.w);
                    *(s16x8*)&Xw[cl * 136 + kofs + quad * 16 + h * 8] = pk;
                }
            }

            // layer 1: [16,128] x [128,64]
            f32x4 a1[4];
            #pragma unroll
            for (int ct = 0; ct < 4; ++ct)
                a1[ct] = (f32x4){b1v[ct], b1v[ct], b1v[ct], b1v[ct]};
            #pragma unroll
            for (int ks = 0; ks < 4; ++ks) {
                s16x8 af = *(const s16x8*)&Xw[cl * 136 + ks * 32 + quad * 8];
                #pragma unroll
                for (int ct = 0; ct < 4; ++ct) {
                    s16x8 bf = *(const s16x8*)&W1t[(ct * 16 + cl) * 136 + ks * 32 + quad * 8];
                    a1[ct] = __builtin_amdgcn_mfma_f32_16x16x32_bf16(af, bf, a1[ct], 0, 0, 0);
                }
            }
            #pragma unroll
            for (int ct = 0; ct < 4; ++ct)
                #pragma unroll
                for (int reg = 0; reg < 4; ++reg)
                    Hw[(quad * 4 + reg) * 72 + ct * 16 + cl] =
                        (short)f2bf(fmaxf(a1[ct][reg], 0.f));

            // layer 2: [16,64] x [64,64]
            f32x4 a2[4];
            #pragma unroll
            for (int ct = 0; ct < 4; ++ct)
                a2[ct] = (f32x4){b2v[ct], b2v[ct], b2v[ct], b2v[ct]};
            #pragma unroll
            for (int ks = 0; ks < 2; ++ks) {
                s16x8 af = *(const s16x8*)&Hw[cl * 72 + ks * 32 + quad * 8];
                #pragma unroll
                for (int ct = 0; ct < 4; ++ct) {
                    s16x8 bf = *(const s16x8*)&W2t[(ct * 16 + cl) * 72 + ks * 32 + quad * 8];
                    a2[ct] = __builtin_amdgcn_mfma_f32_16x16x32_bf16(af, bf, a2[ct], 0, 0, 0);
                }
            }

            // layer 3: per-row dot with W3 (b3 cancels in softmax)
            float p[4];
            #pragma unroll
            for (int reg = 0; reg < 4; ++reg) {
                float s = 0.f;
                #pragma unroll
                for (int ct = 0; ct < 4; ++ct)
                    s += fmaxf(a2[ct][reg], 0.f) * w3v[ct];
                p[reg] = s;
            }
            #pragma unroll
            for (int off = 1; off < 16; off <<= 1)
                #pragma unroll
                for (int reg = 0; reg < 4; ++reg)
                    p[reg] += __shfl_xor(p[reg], off);

            if (cl == 0) {
                #pragma unroll
                for (int reg = 0; reg < 4; ++reg) {
                    int row = quad * 4 + reg;
                    scl[row] = (row < rem) ? p[reg] : -INFINITY;
                }
            }
            __builtin_amdgcn_wave_barrier();

            // online softmax update + PV from LDS u-columns (lane = channel)
            float sv[16];
            #pragma unroll
            for (int r = 0; r < 16; ++r) sv[r] = scl[r];
            float tm = sv[0];
            #pragma unroll
            for (int r = 1; r < 16; ++r) tm = fmaxf(tm, sv[r]);
            const float mN = fmaxf(m, tm);
            const float scale = __expf(m - mN);   // 0 when m == -inf
            S *= scale; acc *= scale;
            #pragma unroll
            for (int r = 0; r < 16; ++r) {
                float wgt = __expf(sv[r] - mN);   // 0 for masked rows
                S += wgt;
                acc = fmaf(wgt, bf2f((unsigned short)Xw[r * 136 + lane]), acc);
            }
            m = mN;
            __builtin_amdgcn_wave_barrier();
        };

        const int nb = curDn < (int)CAP ? curDn : (int)CAP;
        const int ntile = (nb + 15) >> 4;
        for (int t = 0; t < ntile; ++t) {
            const int rem = nb - t * 16;
            int er;
            if (t == 0)   // ids already in flight: select lane min(cl,rem-1) within quad
                er = __shfl(curEraw, (quad << 4) | min(cl, rem - 1));
            else
                er = bucket[(size_t)curN * CAP + t * 16 + min(cl, rem - 1)];
            do_tile(er, rem);
        }
        if (curDn > (int)CAP) {                   // guaranteed-correct slow path
            const int novf = (int)*ovfcnt;        // (expected 0 iterations)
            for (int i = 0; i < novf; ++i)
                if (ovf[2 * i + 1] == curN) do_tile(ovf[2 * i], 1);
        }

        out[(size_t)ni * D + lane] = (curDn > 0) ? acc / S : 0.f;
    }
}

extern "C" void kernel_launch(void* const* d_in, const int* in_sizes, int n_in,
                              void* d_out, int out_size, void* d_ws, size_t ws_size,
                              hipStream_t stream) {
    const float* embed_u = (const float*)d_in[0];
    const float* rep     = (const float*)d_in[1];
    const int*   dst     = (const int*)d_in[2];
    const int*   nodes   = (const int*)d_in[3];
    const float* W1      = (const float*)d_in[4];
    const float* b1      = (const float*)d_in[5];
    const float* W2      = (const float*)d_in[6];
    const float* b2      = (const float*)d_in[7];
    const float* W3      = (const float*)d_in[8];
    float* out = (float*)d_out;
    const int E = in_sizes[2];
    const int B = in_sizes[3];

    char* ws = (char*)d_ws;
    unsigned* slot   = (unsigned*)(ws + 0);                         // [N] never zeroed
    unsigned* deg    = (unsigned*)(ws + 400000);                    // [N]
    unsigned* ovfcnt = (unsigned*)(ws + 800000);                    // [1]
    int*      ovf    = (int*)     (ws + 1024 * 1024);               // [E*2] worst case
    int*      bucket = (int*)     (ws + (size_t)12 * 1024 * 1024);  // [N*CAP] = 25.6 MB

    const int initThreads = (N_NODES > B ? N_NODES : B);

    init_mark_kernel<<<(initThreads + 255) / 256, 256, 0, stream>>>(
        nodes, slot, deg, ovfcnt, B, N_NODES);

    bucket_kernel<<<((E >> 2) + 255) / 256, 256, 0, stream>>>(
        dst, slot, deg, bucket, ovfcnt, ovf, E);

    fused_kernel<<<512, 512, 0, stream>>>(embed_u, rep, W1, b1, W2, b2, W3,
                                          nodes, deg, bucket, ovfcnt, ovf, out, B);
}